// Round 5
// baseline (375.542 us; speedup 1.0000x reference)
//
#include <hip/hip_runtime.h>
#include <hip/hip_bf16.h>

typedef __bf16 bf16_t;
typedef __bf16 bf16x8 __attribute__((ext_vector_type(8)));
typedef __bf16 bf16x4 __attribute__((ext_vector_type(4)));
typedef float f32x4 __attribute__((ext_vector_type(4)));
typedef unsigned int u32;
typedef const __attribute__((address_space(1))) u32* gptr_t;
typedef __attribute__((address_space(3))) u32* lptr_t;

static constexpr int Bb = 16, Ss = 1024, Hh = 768;

// ---- per-batch mask compaction: tok[b][j] = j-th valid s, cnt[b] = count ----
__global__ __launch_bounds__(256) void compact_mask(
    const int* __restrict__ mask, int* __restrict__ tok, int* __restrict__ cnt)
{
    const int b = blockIdx.x;
    const int t = threadIdx.x;
    const int4 m4 = *(const int4*)&mask[(b << 10) + (t << 2)];
    const int c = (m4.x != 0) + (m4.y != 0) + (m4.z != 0) + (m4.w != 0);
    __shared__ int sb[256];
    sb[t] = c;
    __syncthreads();
    for (int off = 1; off < 256; off <<= 1) {
        int v = (t >= off) ? sb[t - off] : 0;
        __syncthreads();
        sb[t] += v;
        __syncthreads();
    }
    int p = sb[t] - c;  // exclusive prefix
    int* tb = tok + (b << 10);
    if (m4.x) tb[p++] = (t << 2) + 0;
    if (m4.y) tb[p++] = (t << 2) + 1;
    if (m4.z) tb[p++] = (t << 2) + 2;
    if (m4.w) tb[p++] = (t << 2) + 3;
    if (t == 255) cnt[b] = sb[255];
}

// ---- conversions + cvec: weights -> bf16 slab, bias pack, x gather-convert,
// ---- and cvec = W2·relu(b1)+b2 (coalesced block-parallel reduction) ----
__global__ __launch_bounds__(256) void cvt_all(
    const float* __restrict__ x,
    const float* __restrict__ w0, const float* __restrict__ w1,
    const float* __restrict__ w2, const float* __restrict__ w3,
    const float* __restrict__ w4,
    const float* __restrict__ bq, const float* __restrict__ bk,
    const float* __restrict__ bv,
    const float* __restrict__ b1, const float* __restrict__ b2,
    const int* __restrict__ tok, const int* __restrict__ cnt,
    bf16_t* __restrict__ xc, bf16_t* __restrict__ wdst, float* __restrict__ bdst,
    float* __restrict__ cvec)
{
    const int bx = blockIdx.x;
    const int t = threadIdx.x;
    if (bx < 2880) {
        int seg = bx / 576;
        const float* src = seg == 0 ? w0 : seg == 1 ? w1 : seg == 2 ? w2 : seg == 3 ? w3 : w4;
        int i = (bx % 576) * 256 + t;
        float4 v = ((const float4*)src)[i];
        bf16x4 o = { (bf16_t)v.x, (bf16_t)v.y, (bf16_t)v.z, (bf16_t)v.w };
        ((bf16x4*)(wdst + (long)seg * 589824))[i] = o;
    } else if (bx < 2889) {
        int i = (bx - 2880) * 256 + t;
        if (i < 2304)
            bdst[i] = i < 768 ? bq[i] : i < 1536 ? bk[i - 768] : bv[i - 1536];
    } else if (bx < 19273) {
        const int idx = bx - 2889;
        const int b = idx >> 10, j = idx & 1023;
        if (j < cnt[b] && t < 192) {
            const int s = tok[(b << 10) + j];
            float4 v = ((const float4*)(x + ((long)((b << 10) + s)) * 768))[t];
            bf16x4 o = { (bf16_t)v.x, (bf16_t)v.y, (bf16_t)v.z, (bf16_t)v.w };
            ((bf16x4*)(xc + ((long)((b << 10) + j)) * 768))[t] = o;
        }
    } else {
        // cvec: 96 blocks x 8 outputs; 32 lanes reduce one W2 row (coalesced)
        const int o = ((bx - 19273) << 3) + (t >> 5);
        const int l = t & 31;
        const float* wr = w4 + (long)o * 768;
        float acc = 0.f;
        for (int h = l; h < 768; h += 32) acc += wr[h] * fmaxf(b1[h], 0.f);
#pragma unroll
        for (int off = 16; off; off >>= 1) acc += __shfl_down(acc, off, 32);
        if (l == 0) cvec[o] = acc + b2[o];
    }
}

// ---------------- async global->LDS 16B ----------------
__device__ __forceinline__ void async_cp16(const void* g, void* l)
{
    __builtin_amdgcn_global_load_lds((gptr_t)g, (lptr_t)l, 16, 0, 0);
}

enum { EG_QKV = 0, EG_SCORE_C = 1, EG_PV = 2, EG_FFN1 = 3, EG_FFN2 = 4 };

#define SBAR __builtin_amdgcn_s_barrier()
#define VMW(n) asm volatile("s_waitcnt vmcnt(" #n ")" ::: "memory")

// C = epi(A * B^T); 128x128 tile, BK=32, 4 waves 2x2, per-wave 64x64,
// mfma_f32_16x16x32_bf16 4x4. XOR-swizzled linear LDS (pre-swizzled GLOBAL
// source; global_load_lds writes lane*16 linear).
// Pipeline: ring-4 LDS (64KB, 2 blocks/CU), stage-ahead-3, vmcnt(4)/iter,
// and REGISTER FRAGMENT READ-AHEAD: during iter t the next tile's fragments
// are ds_read into a second register set while iter t's MFMAs (depending
// only on regs loaded last iter) issue -> ds_read latency off the critical
// path. Two static frag sets (parity-swapped; no runtime reg indexing).
// Invariant: end-of-iter-t vmcnt(4) drains stage(t+2) (read next iter),
// leaves stage(t+3) in flight; buffer overwrite hazards separated by >=2
// barriers. T1 XCD-chunked swizzle (all grids %8==0). Operands compacted
// per batch; m-tiles (score: also n-tiles) early-exit; PV K = ceil32(cnt).
template <int EPI, int BM, int BN>
__global__ __launch_bounds__(256) void mfma_gemm(
    const bf16_t* __restrict__ A, const bf16_t* __restrict__ B,
    const float* __restrict__ bias, const bf16_t* __restrict__ resid,
    const int* __restrict__ tok, const int* __restrict__ cnt,
    void* __restrict__ Cout, bf16_t* __restrict__ out2, bf16_t* __restrict__ out3,
    int K, int lda, int ldb, long sA, long sB, float scale)
{
    // ---- XCD-chunked bijective swizzle (nwg % 8 == 0 for all our grids) ----
    const int gx = gridDim.x, gy = gridDim.y;
    const int nwg = gx * gy * gridDim.z;
    int lid = blockIdx.x + gx * (blockIdx.y + gy * blockIdx.z);
    lid = (lid & 7) * (nwg >> 3) + (lid >> 3);
    const int bxs = lid % gx;
    const int tmp = lid / gx;
    const int bys = tmp % gy;
    const int bz  = tmp / gy;

    const int cb = cnt[bz];
    const int m0 = bys * BM;
    const int n0 = bxs * BN;
    if (m0 >= cb) return;
    if constexpr (EPI == EG_SCORE_C) { if (n0 >= cb) return; }
    const int Kend = (EPI == EG_PV) ? ((cb + 31) & ~31) : K;
    const int nk = Kend >> 5;  // >= 1

    constexpr int PM = BM / 2, PN = BN / 2;     // per-wave tile
    constexpr int MI = PM / 16, NI = PN / 16;   // fragment repeats
    constexpr int ASZ = BM * 32, BSZ = BN * 32; // elements per buffer
    constexpr int NB = 4;                       // ring depth

    __shared__ __align__(16) bf16_t Asl[NB * ASZ];
    __shared__ __align__(16) bf16_t Bsl[NB * BSZ];

    const int tid = threadIdx.x;
    const int wid = tid >> 6;
    const int lane = tid & 63;
    const int wm = wid & 1, wn = wid >> 1;

    const bf16_t* Ab = A + (long)bz * sA;
    const bf16_t* Bp = B + (long)bz * sB;

    // staging: wave w covers rows w*16+(l>>2); global col chunk XOR-preswizzled
    const int srow = (wid << 4) + (lane >> 2);
    const int scol = ((lane & 3) ^ ((lane >> 3) & 3)) << 3;

    const bf16_t* pa0 = Ab + (long)(m0 + srow) * lda + scol;
    const bf16_t* pa1 = Ab + (long)(m0 + 64 + srow) * lda + scol;  // BM==128 only
    const bf16_t* pb0 = Bp + (long)(n0 + srow) * ldb + scol;
    const bf16_t* pb1 = Bp + (long)(n0 + 64 + srow) * ldb + scol;  // BN==128 only

    const int woff = wid << 9;  // wave's 16-row staging base within a buffer

    // fragment read: row=lane&15, kchunk=(lane>>4)^((lane>>1)&3)  (2-way = free)
    const int frag_off = ((lane & 15) << 5) + (((lane >> 4) ^ ((lane >> 1) & 3)) << 3);

    auto stage = [&](int kk, int buf) {
        bf16_t* la = &Asl[buf * ASZ + woff];
        bf16_t* lb = &Bsl[buf * BSZ + woff];
        async_cp16(pa0 + kk, la);
        if constexpr (BM == 128) async_cp16(pa1 + kk, la + 2048);
        async_cp16(pb0 + kk, lb);
        if constexpr (BN == 128) async_cp16(pb1 + kk, lb + 2048);
    };

    f32x4 acc[MI][NI] = {};
    bf16x8 aA[MI], bA[NI], aB[MI], bB[NI];

#define RD_FRAGS(av, bv, buf) do { \
    const int _ca = (buf) * ASZ, _cb2 = (buf) * BSZ; \
    _Pragma("unroll") for (int _i = 0; _i < MI; _i++) \
        av[_i] = *(const bf16x8*)&Asl[_ca + ((wm * MI + _i) << 9) + frag_off]; \
    _Pragma("unroll") for (int _j = 0; _j < NI; _j++) \
        bv[_j] = *(const bf16x8*)&Bsl[_cb2 + ((wn * NI + _j) << 9) + frag_off]; } while (0)

#define MFMA_SET(av, bv) do { \
    _Pragma("unroll") for (int _i = 0; _i < MI; _i++) \
    _Pragma("unroll") for (int _j = 0; _j < NI; _j++) \
        acc[_i][_j] = __builtin_amdgcn_mfma_f32_16x16x32_bf16(av[_i], bv[_j], acc[_i][_j], 0, 0, 0); } while (0)

    // prologue: stage tiles 0..2; ensure 0 and 1 landed, leave 2 in flight
    stage(0, 0);
    if (nk > 1) stage(32, 1);
    if (nk > 2) stage(64, 2);
    __builtin_amdgcn_sched_barrier(0);
    if (nk > 2) { VMW(4); } else { VMW(0); }
    SBAR;
    RD_FRAGS(aA, bA, 0);   // tile 0 -> set A

#pragma unroll 2
    for (int it = 0; it < nk - 1; ++it) {
        // stage 3 tiles ahead into the ring slot that frees this iter
        if (it + 3 < nk) stage((it + 3) << 5, (it + 3) & 3);
        // read-ahead: tile it+1 fragments into the OTHER register set
        if (it & 1) RD_FRAGS(aA, bA, (it + 1) & 3);
        else        RD_FRAGS(aB, bB, (it + 1) & 3);
        __builtin_amdgcn_sched_barrier(0);   // pin reads before MFMAs
        // compute tile it from the CURRENT set (regs loaded last iter)
        if (it & 1) MFMA_SET(aB, bB);
        else        MFMA_SET(aA, bA);
        __builtin_amdgcn_sched_barrier(0);
        // drain stage(it+2) (read next iter); leave stage(it+3) in flight
        if (it + 3 < nk) { VMW(4); } else { VMW(0); }
        SBAR;
    }
    asm volatile("s_waitcnt lgkmcnt(0)" ::: "memory");
    __builtin_amdgcn_sched_barrier(0);
    if (nk & 1) MFMA_SET(aA, bA);   // tile nk-1 lives in set A iff nk-1 even
    else        MFMA_SET(aB, bB);

    // epilogue — C/D per 16x16 tile: col = lane&15, row = (lane>>4)*4 + reg
    const int mb_ = m0 + wm * PM;
    const int nb_ = n0 + wn * PN;
    const int colw = lane & 15;
    const int rowq = (lane >> 4) << 2;

    if constexpr (EPI == EG_QKV) {
        float bj[NI];
#pragma unroll
        for (int j = 0; j < NI; j++) bj[j] = bias[nb_ + (j << 4) + colw];
        if (nb_ < 1536) {
            bf16_t* C = ((nb_ < 768) ? (bf16_t*)Cout : out2) + (long)bz * 786432;
            const int cbase = (nb_ < 768) ? nb_ : nb_ - 768;
#pragma unroll
            for (int i = 0; i < MI; i++)
#pragma unroll
                for (int j = 0; j < NI; j++)
#pragma unroll
                    for (int r = 0; r < 4; r++) {
                        int row = mb_ + (i << 4) + rowq + r;
                        int col = cbase + (j << 4) + colw;
                        C[(long)row * Hh + col] = (bf16_t)fmaxf(acc[i][j][r] + bj[j], 0.f);
                    }
        } else {
            bf16_t* C = out3 + (long)bz * 786432;  // vTc[b][h][jc]
#pragma unroll
            for (int i = 0; i < MI; i++) {
                const int jc0 = mb_ + (i << 4) + rowq;
#pragma unroll
                for (int j = 0; j < NI; j++) {
                    const int col = nb_ - 1536 + (j << 4) + colw;
                    bf16x4 o = { (bf16_t)(acc[i][j][0] + bj[j]), (bf16_t)(acc[i][j][1] + bj[j]),
                                 (bf16_t)(acc[i][j][2] + bj[j]), (bf16_t)(acc[i][j][3] + bj[j]) };
                    *(bf16x4*)&C[(long)col * 1024 + jc0] = o;
                }
            }
        }
    } else if constexpr (EPI == EG_SCORE_C) {
        // computed T = k·q^T (rows=keys); store S = T^T, no mask (all tokens valid)
        bf16_t* C = (bf16_t*)Cout + (long)bz * 1048576;
#pragma unroll
        for (int i = 0; i < MI; i++) {
            const int kbase = mb_ + (i << 4) + rowq;
#pragma unroll
            for (int j = 0; j < NI; j++) {
                const int qrow = nb_ + (j << 4) + colw;
                bf16x4 o = { (bf16_t)(acc[i][j][0] * scale), (bf16_t)(acc[i][j][1] * scale),
                             (bf16_t)(acc[i][j][2] * scale), (bf16_t)(acc[i][j][3] * scale) };
                *(bf16x4*)&C[(long)qrow * 1024 + kbase] = o;
            }
        }
    } else if constexpr (EPI == EG_FFN2) {
        float* outp = (float*)Cout;
        const bf16_t* crow = resid + (long)bz * 786432;
        const int* tb = tok + (bz << 10);
        float bj[NI];
#pragma unroll
        for (int j = 0; j < NI; j++) bj[j] = bias[nb_ + (j << 4) + colw];
#pragma unroll
        for (int i = 0; i < MI; i++)
#pragma unroll
            for (int r = 0; r < 4; r++) {
                const int jq = mb_ + (i << 4) + rowq + r;
                if (jq < cb) {
                    const int s = tb[jq];
                    float* orow = outp + ((long)((bz << 10) + s)) * 768;
                    const bf16_t* cr = crow + (long)jq * 768;
#pragma unroll
                    for (int j = 0; j < NI; j++) {
                        const int col = nb_ + (j << 4) + colw;
                        orow[col] = acc[i][j][r] + bj[j] + (float)cr[col];
                    }
                }
            }
    } else {
        // EG_PV (plain bf16) / EG_FFN1 (relu+bias bf16), compact per-batch
        bf16_t* C = (bf16_t*)Cout + (long)bz * 786432;
        float bj[NI];
#pragma unroll
        for (int j = 0; j < NI; j++) bj[j] = 0.f;
        if constexpr (EPI == EG_FFN1) {
#pragma unroll
            for (int j = 0; j < NI; j++) bj[j] = bias[nb_ + (j << 4) + colw];
        }
#pragma unroll
        for (int i = 0; i < MI; i++)
#pragma unroll
            for (int j = 0; j < NI; j++)
#pragma unroll
                for (int r = 0; r < 4; r++) {
                    int row = mb_ + (i << 4) + rowq + r;
                    int col = nb_ + (j << 4) + colw;
                    float v = acc[i][j][r] + bj[j];
                    if constexpr (EPI == EG_FFN1) v = fmaxf(v, 0.f);
                    C[(long)row * Hh + col] = (bf16_t)v;
                }
    }
#undef RD_FRAGS
#undef MFMA_SET
}

// ---- z=0: softmax over compact keys (validity = col < cnt, no mask loads)
// ---- z=1: fill masked output rows with cvec (disjoint from FFN2's rows)
__global__ __launch_bounds__(256) void softmax_rows(
    bf16_t* __restrict__ S_, const int* __restrict__ cnt,
    const int* __restrict__ mask, const float* __restrict__ cvec,
    float* __restrict__ out)
{
    const int b = blockIdx.y;
    const int t = threadIdx.x;

    if (blockIdx.z == 1) {
        const int s = blockIdx.x;
        if (t >= 192 || mask[(b << 10) + s]) return;
        float4 v = ((const float4*)cvec)[t];
        ((float4*)(out + ((long)((b << 10) + s)) * 768))[t] = v;
        return;
    }

    const int jq = blockIdx.x;
    const int cb = cnt[b];
    if (jq >= cb) return;
    bf16_t* p = S_ + (((long)(b << 10)) + jq) * 1024;
    const int t0 = t << 2;

    bf16x4 v4 = *(const bf16x4*)&p[t0];
    float v0 = (t0 + 0 < cb) ? (float)v4[0] : -1e30f;
    float v1 = (t0 + 1 < cb) ? (float)v4[1] : -1e30f;
    float v2 = (t0 + 2 < cb) ? (float)v4[2] : -1e30f;
    float v3 = (t0 + 3 < cb) ? (float)v4[3] : -1e30f;

    float mx = fmaxf(fmaxf(v0, v1), fmaxf(v2, v3));
#pragma unroll
    for (int off = 32; off; off >>= 1) mx = fmaxf(mx, __shfl_down(mx, off, 64));
    __shared__ float redm[4], reds[4];
    if ((t & 63) == 0) redm[t >> 6] = mx;
    __syncthreads();
    mx = fmaxf(fmaxf(redm[0], redm[1]), fmaxf(redm[2], redm[3]));

    // invalid lanes: exp(-1e30 - mx) underflows to exactly 0
    float e0 = __expf(v0 - mx), e1 = __expf(v1 - mx);
    float e2 = __expf(v2 - mx), e3 = __expf(v3 - mx);
    float sm = e0 + e1 + e2 + e3;
#pragma unroll
    for (int off = 32; off; off >>= 1) sm += __shfl_down(sm, off, 64);
    if ((t & 63) == 0) reds[t >> 6] = sm;
    __syncthreads();
    sm = reds[0] + reds[1] + reds[2] + reds[3];

    const float inv = 1.f / sm;
    bf16x4 o = { (bf16_t)(e0 * inv), (bf16_t)(e1 * inv),
                 (bf16_t)(e2 * inv), (bf16_t)(e3 * inv) };
    *(bf16x4*)&p[t0] = o;
}

extern "C" void kernel_launch(void* const* d_in, const int* in_sizes, int n_in,
                              void* d_out, int out_size, void* d_ws, size_t ws_size,
                              hipStream_t stream)
{
    const float* x  = (const float*)d_in[0];
    const int* mask = (const int*)d_in[1];
    const float* Wq = (const float*)d_in[2];
    const float* bq = (const float*)d_in[3];
    const float* Wk = (const float*)d_in[4];
    const float* bk = (const float*)d_in[5];
    const float* Wv = (const float*)d_in[6];
    const float* bv = (const float*)d_in[7];
    const float* W1 = (const float*)d_in[8];
    const float* b1 = (const float*)d_in[9];
    const float* W2 = (const float*)d_in[10];
    const float* b2 = (const float*)d_in[11];
    float* out = (float*)d_out;

    // workspace layout (~140.2 MB)
    char* w = (char*)d_ws;
    bf16_t* xc   = (bf16_t*)(w + 0);            // [16][1024][768] compact, reused as ctxc
    bf16_t* qc   = (bf16_t*)(w + 25165824);     // reused as h1c
    bf16_t* kc   = (bf16_t*)(w + 50331648);
    bf16_t* vTc  = (bf16_t*)(w + 75497472);     // [16][768][1024] compact cols
    bf16_t* sc   = (bf16_t*)(w + 100663296);    // [16][1024][1024] bf16
    bf16_t* wqkv = (bf16_t*)(w + 134217728);    // [2304,768] = Wq|Wk|Wv
    bf16_t* w1b  = (bf16_t*)(w + 137756672);
    bf16_t* w2b  = (bf16_t*)(w + 138936320);
    float*  bqkv = (float*) (w + 140115968);    // [2304]
    int*    tok  = (int*)   (w + 140125184);    // [16][1024]
    int*    cnt  = (int*)   (w + 140190720);    // [16]
    float*  cvec = (float*) (w + 140190784);    // [768]
    bf16_t* ctxc = xc;
    bf16_t* h1c  = qc;

    const float inv_sqrt_h = 0.036084391824351615f; // 1/sqrt(768)
    dim3 blk(256);

    compact_mask<<<16, blk, 0, stream>>>(mask, tok, cnt);
    cvt_all<<<19369, blk, 0, stream>>>(x, Wq, Wk, Wv, W1, W2, bq, bk, bv, b1, b2,
                                       tok, cnt, xc, wqkv, bqkv, cvec);

    // qc|kc|vTc = epi(xc · [Wq|Wk|Wv]^T + bqkv), compact rows
    mfma_gemm<EG_QKV, 128, 128><<<dim3(18, 8, 16), blk, 0, stream>>>(
        xc, wqkv, bqkv, nullptr, tok, cnt, qc, kc, vTc,
        768, 768, 768, 786432, 0, 1.f);

    // sc[jq][jk] = (kc·qc^T)^T * scale  (both dims compact)
    mfma_gemm<EG_SCORE_C, 128, 128><<<dim3(8, 8, 16), blk, 0, stream>>>(
        kc, qc, nullptr, nullptr, tok, cnt, sc, nullptr, nullptr,
        768, 768, 768, 786432, 786432, inv_sqrt_h);

    // z=0: softmax over valid keys in place; z=1: masked out rows = cvec
    softmax_rows<<<dim3(1024, 16, 2), blk, 0, stream>>>(sc, cnt, mask, cvec, out);

    // ctxc = sc · vTc^T   (K = ceil32(cnt) per batch)
    mfma_gemm<EG_PV, 128, 128><<<dim3(6, 8, 16), blk, 0, stream>>>(
        sc, vTc, nullptr, nullptr, tok, cnt, ctxc, nullptr, nullptr,
        0, 1024, 1024, 1048576, 786432, 1.f);

    // h1c = relu(ctxc · W1^T + b1)
    mfma_gemm<EG_FFN1, 128, 128><<<dim3(6, 8, 16), blk, 0, stream>>>(
        ctxc, w1b, b1, nullptr, tok, cnt, h1c, nullptr, nullptr,
        768, 768, 768, 786432, 0, 1.f);

    // out[b][tok[jq]] = h1c · W2^T + b2 + ctxc   (scatter, fp32)
    mfma_gemm<EG_FFN2, 128, 128><<<dim3(6, 8, 16), blk, 0, stream>>>(
        h1c, w2b, b2, ctxc, tok, cnt, out, nullptr, nullptr,
        768, 768, 768, 786432, 0, 1.f);
}

// Round 6
// 282.235 us; speedup vs baseline: 1.3306x; 1.3306x over previous
//
#include <hip/hip_runtime.h>
#include <hip/hip_bf16.h>

typedef __bf16 bf16_t;
typedef __bf16 bf16x8 __attribute__((ext_vector_type(8)));
typedef __bf16 bf16x4 __attribute__((ext_vector_type(4)));
typedef float f32x4 __attribute__((ext_vector_type(4)));
typedef unsigned int u32;
typedef const __attribute__((address_space(1))) u32* gptr_t;
typedef __attribute__((address_space(3))) u32* lptr_t;

static constexpr int Bb = 16, Ss = 1024, Hh = 768;

// ---- per-batch mask compaction: tok[b][j] = j-th valid s, cnt[b] = count ----
__global__ __launch_bounds__(256) void compact_mask(
    const int* __restrict__ mask, int* __restrict__ tok, int* __restrict__ cnt)
{
    const int b = blockIdx.x;
    const int t = threadIdx.x;
    const int4 m4 = *(const int4*)&mask[(b << 10) + (t << 2)];
    const int c = (m4.x != 0) + (m4.y != 0) + (m4.z != 0) + (m4.w != 0);
    __shared__ int sb[256];
    sb[t] = c;
    __syncthreads();
    for (int off = 1; off < 256; off <<= 1) {
        int v = (t >= off) ? sb[t - off] : 0;
        __syncthreads();
        sb[t] += v;
        __syncthreads();
    }
    int p = sb[t] - c;  // exclusive prefix
    int* tb = tok + (b << 10);
    if (m4.x) tb[p++] = (t << 2) + 0;
    if (m4.y) tb[p++] = (t << 2) + 1;
    if (m4.z) tb[p++] = (t << 2) + 2;
    if (m4.w) tb[p++] = (t << 2) + 3;
    if (t == 255) cnt[b] = sb[255];
}

// ---- conversions + cvec: weights -> bf16 slab, bias pack, x gather-convert,
// ---- and cvec = W2·relu(b1)+b2 (coalesced block-parallel reduction) ----
__global__ __launch_bounds__(256) void cvt_all(
    const float* __restrict__ x,
    const float* __restrict__ w0, const float* __restrict__ w1,
    const float* __restrict__ w2, const float* __restrict__ w3,
    const float* __restrict__ w4,
    const float* __restrict__ bq, const float* __restrict__ bk,
    const float* __restrict__ bv,
    const float* __restrict__ b1, const float* __restrict__ b2,
    const int* __restrict__ tok, const int* __restrict__ cnt,
    bf16_t* __restrict__ xc, bf16_t* __restrict__ wdst, float* __restrict__ bdst,
    float* __restrict__ cvec)
{
    const int bx = blockIdx.x;
    const int t = threadIdx.x;
    if (bx < 2880) {
        int seg = bx / 576;
        const float* src = seg == 0 ? w0 : seg == 1 ? w1 : seg == 2 ? w2 : seg == 3 ? w3 : w4;
        int i = (bx % 576) * 256 + t;
        float4 v = ((const float4*)src)[i];
        bf16x4 o = { (bf16_t)v.x, (bf16_t)v.y, (bf16_t)v.z, (bf16_t)v.w };
        ((bf16x4*)(wdst + (long)seg * 589824))[i] = o;
    } else if (bx < 2889) {
        int i = (bx - 2880) * 256 + t;
        if (i < 2304)
            bdst[i] = i < 768 ? bq[i] : i < 1536 ? bk[i - 768] : bv[i - 1536];
    } else if (bx < 19273) {
        const int idx = bx - 2889;
        const int b = idx >> 10, j = idx & 1023;
        if (j < cnt[b] && t < 192) {
            const int s = tok[(b << 10) + j];
            float4 v = ((const float4*)(x + ((long)((b << 10) + s)) * 768))[t];
            bf16x4 o = { (bf16_t)v.x, (bf16_t)v.y, (bf16_t)v.z, (bf16_t)v.w };
            ((bf16x4*)(xc + ((long)((b << 10) + j)) * 768))[t] = o;
        }
    } else {
        // cvec: 96 blocks x 8 outputs; 32 lanes reduce one W2 row (coalesced)
        const int o = ((bx - 19273) << 3) + (t >> 5);
        const int l = t & 31;
        const float* wr = w4 + (long)o * 768;
        float acc = 0.f;
        for (int h = l; h < 768; h += 32) acc += wr[h] * fmaxf(b1[h], 0.f);
#pragma unroll
        for (int off = 16; off; off >>= 1) acc += __shfl_down(acc, off, 32);
        if (l == 0) cvec[o] = acc + b2[o];
    }
}

// ---------------- async global->LDS 16B ----------------
__device__ __forceinline__ void async_cp16(const void* g, void* l)
{
    __builtin_amdgcn_global_load_lds((gptr_t)g, (lptr_t)l, 16, 0, 0);
}

enum { EG_QKV = 0, EG_SCORE_C = 1, EG_PV = 2, EG_FFN1 = 3, EG_FFN2 = 4 };

#define SBAR __builtin_amdgcn_s_barrier()
#define VMW(n) asm volatile("s_waitcnt vmcnt(" #n ")" ::: "memory")

// C = epi(A * B^T); 128x128 tile, BK=32, *** 8 waves (512 thr) *** per-wave
// 32x64 (wm=wid&3 M-quadrant, wn=wid>>2 N-half), MI=2 NI=4, 8 MFMA : 6
// ds_read_b128 per wave-iter. Same tile-level LDS traffic and MFMA count as
// the verified 4-wave R3 kernel, but 2x waves/CU -> latency hiding for the
// low-block-count GEMMs (score 1/CU, PV/FFN 1.5/CU were wave-starved).
// Schedule = R3 verbatim: ring-3 LDS (48KB), stage-ahead-2, counted
// s_waitcnt vmcnt(2) (2 loads/wave/stage) + raw s_barrier, ONE barrier/iter.
// Hazards: stage(it+2) overwrites buf((it+2)%3), whose ds_reads all completed
// before the barrier ending iter it-1; VMW(2) at end of iter t drains
// stage(t+1), leaves stage(t+2) in flight. XOR-swizzled linear LDS
// (pre-swizzled GLOBAL source; global_load_lds writes lane*16 linear).
// T1 XCD-chunked swizzle (all grids %8==0). Operands compacted per batch;
// m-tiles (score: also n-tiles) early-exit; PV K = ceil32(cnt).
template <int EPI, int BM, int BN>
__global__ __launch_bounds__(512) void mfma_gemm(
    const bf16_t* __restrict__ A, const bf16_t* __restrict__ B,
    const float* __restrict__ bias, const bf16_t* __restrict__ resid,
    const int* __restrict__ tok, const int* __restrict__ cnt,
    void* __restrict__ Cout, bf16_t* __restrict__ out2, bf16_t* __restrict__ out3,
    int K, int lda, int ldb, long sA, long sB, float scale)
{
    // ---- XCD-chunked bijective swizzle (nwg % 8 == 0 for all our grids) ----
    const int gx = gridDim.x, gy = gridDim.y;
    const int nwg = gx * gy * gridDim.z;
    int lid = blockIdx.x + gx * (blockIdx.y + gy * blockIdx.z);
    lid = (lid & 7) * (nwg >> 3) + (lid >> 3);
    const int bxs = lid % gx;
    const int tmp = lid / gx;
    const int bys = tmp % gy;
    const int bz  = tmp / gy;

    const int cb = cnt[bz];
    const int m0 = bys * BM;
    const int n0 = bxs * BN;
    if (m0 >= cb) return;
    if constexpr (EPI == EG_SCORE_C) { if (n0 >= cb) return; }
    const int Kend = (EPI == EG_PV) ? ((cb + 31) & ~31) : K;
    const int nk = Kend >> 5;  // >= 1

    constexpr int MI = 2, NI = 4;               // per-wave 32x64 of the 128x128
    constexpr int ASZ = BM * 32, BSZ = BN * 32; // elements per buffer
    constexpr int NB = 3;                       // ring depth

    __shared__ __align__(16) bf16_t Asl[NB * ASZ];
    __shared__ __align__(16) bf16_t Bsl[NB * BSZ];

    const int tid = threadIdx.x;
    const int wid = tid >> 6;     // 0..7
    const int lane = tid & 63;
    const int wm = wid & 3, wn = wid >> 2;

    const bf16_t* Ab = A + (long)bz * sA;
    const bf16_t* Bp = B + (long)bz * sB;

    // staging: wave w covers rows w*16+(l>>2) (8 waves -> 128 rows);
    // global col chunk XOR-preswizzled (rule 21: source-and-read same XOR)
    const int srow = (wid << 4) + (lane >> 2);
    const int scol = ((lane & 3) ^ ((lane >> 3) & 3)) << 3;

    const bf16_t* pa0 = Ab + (long)(m0 + srow) * lda + scol;
    const bf16_t* pb0 = Bp + (long)(n0 + srow) * ldb + scol;

    const int woff = wid << 9;  // wave's 16-row staging base within a buffer

    // fragment read: row=lane&15, kchunk=(lane>>4)^((lane>>1)&3)  (2-way = free)
    const int frag_off = ((lane & 15) << 5) + (((lane >> 4) ^ ((lane >> 1) & 3)) << 3);

    auto stage = [&](int kk, int buf) {
        async_cp16(pa0 + kk, &Asl[buf * ASZ + woff]);
        async_cp16(pb0 + kk, &Bsl[buf * BSZ + woff]);
    };

    f32x4 acc[MI][NI] = {};

    // prologue: stage tiles 0,1; drain stage(0), leave stage(1) in flight
    stage(0, 0);
    if (nk > 1) stage(32, 1);
    __builtin_amdgcn_sched_barrier(0);
    if (nk > 1) { VMW(2); } else { VMW(0); }
    SBAR;

    int cur = 0;
    for (int it = 0; it < nk; ++it) {
        // stage 2 tiles ahead into the ring slot read in iter it-1
        if (it + 2 < nk) {
            int tgt = cur + 2; if (tgt >= NB) tgt -= NB;
            stage((it + 2) << 5, tgt);
        }

        // compute current buffer
        const int cba = cur * ASZ, cbb = cur * BSZ;
        bf16x8 af[MI], bfr[NI];
#pragma unroll
        for (int i = 0; i < MI; i++)
            af[i] = *(const bf16x8*)&Asl[cba + ((wm * MI + i) << 9) + frag_off];
#pragma unroll
        for (int j = 0; j < NI; j++)
            bfr[j] = *(const bf16x8*)&Bsl[cbb + ((wn * NI + j) << 9) + frag_off];
#pragma unroll
        for (int i = 0; i < MI; i++)
#pragma unroll
            for (int j = 0; j < NI; j++)
                acc[i][j] = __builtin_amdgcn_mfma_f32_16x16x32_bf16(af[i], bfr[j], acc[i][j], 0, 0, 0);

        // counted wait: stage(it+1) must be done; stage(it+2) stays in flight
        __builtin_amdgcn_sched_barrier(0);
        if (it + 1 < nk) {
            if (it + 2 < nk) { VMW(2); } else { VMW(0); }
            SBAR;
        }
        cur = (cur + 1 == NB) ? 0 : cur + 1;
    }

    // epilogue — C/D per 16x16 tile: col = lane&15, row = (lane>>4)*4 + reg
    const int mb_ = m0 + wm * 32;
    const int nb_ = n0 + wn * 64;
    const int colw = lane & 15;
    const int rowq = (lane >> 4) << 2;

    if constexpr (EPI == EG_QKV) {
        float bj[NI];
#pragma unroll
        for (int j = 0; j < NI; j++) bj[j] = bias[nb_ + (j << 4) + colw];
        if (nb_ < 1536) {
            bf16_t* C = ((nb_ < 768) ? (bf16_t*)Cout : out2) + (long)bz * 786432;
            const int cbase = (nb_ < 768) ? nb_ : nb_ - 768;
#pragma unroll
            for (int i = 0; i < MI; i++)
#pragma unroll
                for (int j = 0; j < NI; j++)
#pragma unroll
                    for (int r = 0; r < 4; r++) {
                        int row = mb_ + (i << 4) + rowq + r;
                        int col = cbase + (j << 4) + colw;
                        C[(long)row * Hh + col] = (bf16_t)fmaxf(acc[i][j][r] + bj[j], 0.f);
                    }
        } else {
            bf16_t* C = out3 + (long)bz * 786432;  // vTc[b][h][jc]
#pragma unroll
            for (int i = 0; i < MI; i++) {
                const int jc0 = mb_ + (i << 4) + rowq;
#pragma unroll
                for (int j = 0; j < NI; j++) {
                    const int col = nb_ - 1536 + (j << 4) + colw;
                    bf16x4 o = { (bf16_t)(acc[i][j][0] + bj[j]), (bf16_t)(acc[i][j][1] + bj[j]),
                                 (bf16_t)(acc[i][j][2] + bj[j]), (bf16_t)(acc[i][j][3] + bj[j]) };
                    *(bf16x4*)&C[(long)col * 1024 + jc0] = o;
                }
            }
        }
    } else if constexpr (EPI == EG_SCORE_C) {
        // computed T = k·q^T (rows=keys); store S = T^T, no mask (all tokens valid)
        bf16_t* C = (bf16_t*)Cout + (long)bz * 1048576;
#pragma unroll
        for (int i = 0; i < MI; i++) {
            const int kbase = mb_ + (i << 4) + rowq;
#pragma unroll
            for (int j = 0; j < NI; j++) {
                const int qrow = nb_ + (j << 4) + colw;
                bf16x4 o = { (bf16_t)(acc[i][j][0] * scale), (bf16_t)(acc[i][j][1] * scale),
                             (bf16_t)(acc[i][j][2] * scale), (bf16_t)(acc[i][j][3] * scale) };
                *(bf16x4*)&C[(long)qrow * 1024 + kbase] = o;
            }
        }
    } else if constexpr (EPI == EG_FFN2) {
        float* outp = (float*)Cout;
        const bf16_t* crow = resid + (long)bz * 786432;
        const int* tb = tok + (bz << 10);
        float bj[NI];
#pragma unroll
        for (int j = 0; j < NI; j++) bj[j] = bias[nb_ + (j << 4) + colw];
#pragma unroll
        for (int i = 0; i < MI; i++)
#pragma unroll
            for (int r = 0; r < 4; r++) {
                const int jq = mb_ + (i << 4) + rowq + r;
                if (jq < cb) {
                    const int s = tb[jq];
                    float* orow = outp + ((long)((bz << 10) + s)) * 768;
                    const bf16_t* cr = crow + (long)jq * 768;
#pragma unroll
                    for (int j = 0; j < NI; j++) {
                        const int col = nb_ + (j << 4) + colw;
                        orow[col] = acc[i][j][r] + bj[j] + (float)cr[col];
                    }
                }
            }
    } else {
        // EG_PV (plain bf16) / EG_FFN1 (relu+bias bf16), compact per-batch
        bf16_t* C = (bf16_t*)Cout + (long)bz * 786432;
        float bj[NI];
#pragma unroll
        for (int j = 0; j < NI; j++) bj[j] = 0.f;
        if constexpr (EPI == EG_FFN1) {
#pragma unroll
            for (int j = 0; j < NI; j++) bj[j] = bias[nb_ + (j << 4) + colw];
        }
#pragma unroll
        for (int i = 0; i < MI; i++)
#pragma unroll
            for (int j = 0; j < NI; j++)
#pragma unroll
                for (int r = 0; r < 4; r++) {
                    int row = mb_ + (i << 4) + rowq + r;
                    int col = nb_ + (j << 4) + colw;
                    float v = acc[i][j][r] + bj[j];
                    if constexpr (EPI == EG_FFN1) v = fmaxf(v, 0.f);
                    C[(long)row * Hh + col] = (bf16_t)v;
                }
    }
}

// ---- z=0: softmax over compact keys (validity = col < cnt, no mask loads)
// ---- z=1: fill masked output rows with cvec (disjoint from FFN2's rows)
__global__ __launch_bounds__(256) void softmax_rows(
    bf16_t* __restrict__ S_, const int* __restrict__ cnt,
    const int* __restrict__ mask, const float* __restrict__ cvec,
    float* __restrict__ out)
{
    const int b = blockIdx.y;
    const int t = threadIdx.x;

    if (blockIdx.z == 1) {
        const int s = blockIdx.x;
        if (t >= 192 || mask[(b << 10) + s]) return;
        float4 v = ((const float4*)cvec)[t];
        ((float4*)(out + ((long)((b << 10) + s)) * 768))[t] = v;
        return;
    }

    const int jq = blockIdx.x;
    const int cb = cnt[b];
    if (jq >= cb) return;
    bf16_t* p = S_ + (((long)(b << 10)) + jq) * 1024;
    const int t0 = t << 2;

    bf16x4 v4 = *(const bf16x4*)&p[t0];
    float v0 = (t0 + 0 < cb) ? (float)v4[0] : -1e30f;
    float v1 = (t0 + 1 < cb) ? (float)v4[1] : -1e30f;
    float v2 = (t0 + 2 < cb) ? (float)v4[2] : -1e30f;
    float v3 = (t0 + 3 < cb) ? (float)v4[3] : -1e30f;

    float mx = fmaxf(fmaxf(v0, v1), fmaxf(v2, v3));
#pragma unroll
    for (int off = 32; off; off >>= 1) mx = fmaxf(mx, __shfl_down(mx, off, 64));
    __shared__ float redm[4], reds[4];
    if ((t & 63) == 0) redm[t >> 6] = mx;
    __syncthreads();
    mx = fmaxf(fmaxf(redm[0], redm[1]), fmaxf(redm[2], redm[3]));

    // invalid lanes: exp(-1e30 - mx) underflows to exactly 0
    float e0 = __expf(v0 - mx), e1 = __expf(v1 - mx);
    float e2 = __expf(v2 - mx), e3 = __expf(v3 - mx);
    float sm = e0 + e1 + e2 + e3;
#pragma unroll
    for (int off = 32; off; off >>= 1) sm += __shfl_down(sm, off, 64);
    if ((t & 63) == 0) reds[t >> 6] = sm;
    __syncthreads();
    sm = reds[0] + reds[1] + reds[2] + reds[3];

    const float inv = 1.f / sm;
    bf16x4 o = { (bf16_t)(e0 * inv), (bf16_t)(e1 * inv),
                 (bf16_t)(e2 * inv), (bf16_t)(e3 * inv) };
    *(bf16x4*)&p[t0] = o;
}

extern "C" void kernel_launch(void* const* d_in, const int* in_sizes, int n_in,
                              void* d_out, int out_size, void* d_ws, size_t ws_size,
                              hipStream_t stream)
{
    const float* x  = (const float*)d_in[0];
    const int* mask = (const int*)d_in[1];
    const float* Wq = (const float*)d_in[2];
    const float* bq = (const float*)d_in[3];
    const float* Wk = (const float*)d_in[4];
    const float* bk = (const float*)d_in[5];
    const float* Wv = (const float*)d_in[6];
    const float* bv = (const float*)d_in[7];
    const float* W1 = (const float*)d_in[8];
    const float* b1 = (const float*)d_in[9];
    const float* W2 = (const float*)d_in[10];
    const float* b2 = (const float*)d_in[11];
    float* out = (float*)d_out;

    // workspace layout (~140.2 MB)
    char* w = (char*)d_ws;
    bf16_t* xc   = (bf16_t*)(w + 0);            // [16][1024][768] compact, reused as ctxc
    bf16_t* qc   = (bf16_t*)(w + 25165824);     // reused as h1c
    bf16_t* kc   = (bf16_t*)(w + 50331648);
    bf16_t* vTc  = (bf16_t*)(w + 75497472);     // [16][768][1024] compact cols
    bf16_t* sc   = (bf16_t*)(w + 100663296);    // [16][1024][1024] bf16
    bf16_t* wqkv = (bf16_t*)(w + 134217728);    // [2304,768] = Wq|Wk|Wv
    bf16_t* w1b  = (bf16_t*)(w + 137756672);
    bf16_t* w2b  = (bf16_t*)(w + 138936320);
    float*  bqkv = (float*) (w + 140115968);    // [2304]
    int*    tok  = (int*)   (w + 140125184);    // [16][1024]
    int*    cnt  = (int*)   (w + 140190720);    // [16]
    float*  cvec = (float*) (w + 140190784);    // [768]
    bf16_t* ctxc = xc;
    bf16_t* h1c  = qc;

    const float inv_sqrt_h = 0.036084391824351615f; // 1/sqrt(768)
    dim3 blk(256);
    dim3 blk8(512);

    compact_mask<<<16, blk, 0, stream>>>(mask, tok, cnt);
    cvt_all<<<19369, blk, 0, stream>>>(x, Wq, Wk, Wv, W1, W2, bq, bk, bv, b1, b2,
                                       tok, cnt, xc, wqkv, bqkv, cvec);

    // qc|kc|vTc = epi(xc · [Wq|Wk|Wv]^T + bqkv), compact rows
    mfma_gemm<EG_QKV, 128, 128><<<dim3(18, 8, 16), blk8, 0, stream>>>(
        xc, wqkv, bqkv, nullptr, tok, cnt, qc, kc, vTc,
        768, 768, 768, 786432, 0, 1.f);

    // sc[jq][jk] = (kc·qc^T)^T * scale  (both dims compact)
    mfma_gemm<EG_SCORE_C, 128, 128><<<dim3(8, 8, 16), blk8, 0, stream>>>(
        kc, qc, nullptr, nullptr, tok, cnt, sc, nullptr, nullptr,
        768, 768, 768, 786432, 786432, inv_sqrt_h);

    // z=0: softmax over valid keys in place; z=1: masked out rows = cvec
    softmax_rows<<<dim3(1024, 16, 2), blk, 0, stream>>>(sc, cnt, mask, cvec, out);

    // ctxc = sc · vTc^T   (K = ceil32(cnt) per batch)
    mfma_gemm<EG_PV, 128, 128><<<dim3(6, 8, 16), blk8, 0, stream>>>(
        sc, vTc, nullptr, nullptr, tok, cnt, ctxc, nullptr, nullptr,
        0, 1024, 1024, 1048576, 786432, 1.f);

    // h1c = relu(ctxc · W1^T + b1)
    mfma_gemm<EG_FFN1, 128, 128><<<dim3(6, 8, 16), blk8, 0, stream>>>(
        ctxc, w1b, b1, nullptr, tok, cnt, h1c, nullptr, nullptr,
        768, 768, 768, 786432, 0, 1.f);

    // out[b][tok[jq]] = h1c · W2^T + b2 + ctxc   (scatter, fp32)
    mfma_gemm<EG_FFN2, 128, 128><<<dim3(6, 8, 16), blk8, 0, stream>>>(
        h1c, w2b, b2, ctxc, tok, cnt, out, nullptr, nullptr,
        768, 768, 768, 786432, 0, 1.f);
}